// Round 4
// baseline (198.261 us; speedup 1.0000x reference)
//
#include <hip/hip_runtime.h>

#define NODE_DIM 128
#define OUT_DIM  64
#define NEG_SLOPE 0.01f

__device__ __forceinline__ unsigned short f2bf(float f) {
    unsigned u = __float_as_uint(f);
    unsigned r = (u + 0x7FFFu + ((u >> 16) & 1u)) >> 16;
    return (unsigned short)r;
}
__device__ __forceinline__ float bf2f(unsigned short v) {
    return __uint_as_float((unsigned)v << 16);
}

// ---- K1 (fused): blocks [0,PB): projection (no LDS); blocks [PB,..): count+rank
// Proj: lane = out dim d; each wave owns 8 nodes. h reads are wave-uniform,
// W reads are coalesced per-lane (L1-resident 32 KB). Inner loop = pure FMA.
__global__ __launch_bounds__(256) void k_proj_count(const float* __restrict__ h,
                                                    const float* __restrict__ Wf,
                                                    const float* __restrict__ Wa,
                                                    unsigned short* __restrict__ zbf,
                                                    float* __restrict__ s_src,
                                                    float* __restrict__ s_dst,
                                                    const int* __restrict__ dst,
                                                    int* __restrict__ deg,
                                                    int* __restrict__ rank,
                                                    int N, int E, int PB, int CB) {
    if (blockIdx.x >= (unsigned)PB) {
        int nthreads = CB * 256;
        for (int i = (blockIdx.x - PB) * 256 + threadIdx.x; i < E; i += nthreads)
            rank[i] = atomicAdd(deg + dst[i], 1);
        return;
    }
    const int t = threadIdx.x;
    const int d = t & 63;
    const int w = __builtin_amdgcn_readfirstlane(t >> 6);
    const int node0 = blockIdx.x * 32 + w * 8;   // this wave's 8 nodes

    // clamped (always-valid) row pointers; OOB results discarded at store
    const float* rowp[8];
    #pragma unroll
    for (int n = 0; n < 8; ++n) {
        int nn = node0 + n; if (nn > N - 1) nn = N - 1;
        rowp[n] = h + (size_t)nn * NODE_DIM;
    }

    float acc[8];
    #pragma unroll
    for (int n = 0; n < 8; ++n) acc[n] = 0.f;

    #pragma unroll
    for (int k0 = 0; k0 < NODE_DIM; k0 += 8) {
        float wv[8];
        #pragma unroll
        for (int kk = 0; kk < 8; ++kk) wv[kk] = Wf[(k0 + kk) * OUT_DIM + d];
        #pragma unroll
        for (int n = 0; n < 8; ++n) {
            #pragma unroll
            for (int kk = 0; kk < 8; ++kk)
                acc[n] = fmaf(rowp[n][k0 + kk], wv[kk], acc[n]);
        }
    }

    const float was = Wa[d];
    const float wad = Wa[OUT_DIM + d];
    #pragma unroll
    for (int n = 0; n < 8; ++n) {
        int nn = node0 + n;
        if (nn < N) zbf[(size_t)nn * OUT_DIM + d] = f2bf(acc[n]);
        float ps = acc[n] * was;
        float pd = acc[n] * wad;
        #pragma unroll
        for (int off = 32; off > 0; off >>= 1) {
            ps += __shfl_xor(ps, off, 64);
            pd += __shfl_xor(pd, off, 64);
        }
        if (d == 0 && nn < N) { s_src[nn] = ps; s_dst[nn] = pd; }
    }
}

// ---- K2: per-block exclusive scan of deg -> rstart(local); bsum[b] = total
__global__ __launch_bounds__(256) void k_scan_local(const int* __restrict__ deg,
                                                    int* __restrict__ rstart,
                                                    int* __restrict__ bsum, int N) {
    __shared__ int s[256];
    int i = blockIdx.x * 256 + threadIdx.x;
    int t = threadIdx.x;
    int v = (i < N) ? deg[i] : 0;
    s[t] = v;
    __syncthreads();
    #pragma unroll
    for (int off = 1; off < 256; off <<= 1) {
        int u = (t >= off) ? s[t - off] : 0;
        __syncthreads();
        s[t] += u;
        __syncthreads();
    }
    if (i < N) rstart[i] = s[t] - v;
    if (t == 255) bsum[blockIdx.x] = s[255];
}

// ---- K3: every block redundantly scans the spine, adds its offset
__global__ __launch_bounds__(256) void k_scan_add(int* __restrict__ rstart,
                                                  const int* __restrict__ bsum,
                                                  int N, int nb) {
    __shared__ int s[256];
    int t = threadIdx.x;
    s[t] = (t < nb) ? bsum[t] : 0;
    __syncthreads();
    #pragma unroll
    for (int off = 1; off < 256; off <<= 1) {
        int u = (t >= off) ? s[t - off] : 0;
        __syncthreads();
        s[t] += u;
        __syncthreads();
    }
    int boff = (blockIdx.x > 0) ? s[blockIdx.x - 1] : 0;
    int i = blockIdx.x * 256 + t;
    if (i < N) rstart[i] += boff;
}

// ---- K4: place src index at rstart[dst] + rank  (4 B records, no atomics)
__global__ __launch_bounds__(256) void k_place(const int* __restrict__ src,
                                               const int* __restrict__ dst,
                                               const int* __restrict__ rank,
                                               const int* __restrict__ rstart,
                                               int* __restrict__ spk, int E) {
    int i = blockIdx.x * 256 + threadIdx.x;
    if (i >= E) return;
    spk[rstart[dst[i]] + rank[i]] = src[i];
}

// ---- K5: one wave per dst node; recompute x = exp(leaky(e)) lane-parallel
__global__ __launch_bounds__(256) void k_agg(const int* __restrict__ rstart,
                                             const int* __restrict__ deg,
                                             const int* __restrict__ spk,
                                             const float* __restrict__ s_src,
                                             const float* __restrict__ s_dst,
                                             const unsigned short* __restrict__ zbf,
                                             float* __restrict__ out, int N) {
    int node = blockIdx.x * 4 + (threadIdx.x >> 6);
    int lane = threadIdx.x & 63;
    if (node >= N) return;
    int rs = rstart[node];
    int dg = deg[node];
    float sdst = s_dst[node];
    const int* pk = spk + rs;
    float acc = 0.f, den = 0.f;
    for (int base = 0; base < dg; base += 64) {
        int m = dg - base; if (m > 64) m = 64;
        int sl = 0; float xl = 0.f;
        if (lane < m) {
            sl = pk[base + lane];
            float e = s_src[sl] + sdst;
            e = (e > 0.f) ? e : e * NEG_SLOPE;
            xl = __expf(e);
        }
        den += xl;
        int j = 0;
        for (; j + 7 < m; j += 8) {
            int ss[8]; float xx[8], zz[8];
            #pragma unroll
            for (int u = 0; u < 8; ++u) {
                ss[u] = __shfl(sl, j + u, 64);
                xx[u] = __shfl(xl, j + u, 64);
            }
            #pragma unroll
            for (int u = 0; u < 8; ++u)
                zz[u] = bf2f(zbf[(size_t)ss[u] * OUT_DIM + lane]);
            #pragma unroll
            for (int u = 0; u < 8; ++u)
                acc = fmaf(xx[u], zz[u], acc);
        }
        for (; j < m; ++j) {
            int s0 = __shfl(sl, j, 64);
            float x0 = __shfl(xl, j, 64);
            acc = fmaf(x0, bf2f(zbf[(size_t)s0 * OUT_DIM + lane]), acc);
        }
    }
    #pragma unroll
    for (int off = 32; off > 0; off >>= 1) den += __shfl_xor(den, off, 64);
    out[(size_t)node * OUT_DIM + lane] = (dg > 0) ? acc / den : 0.f;
}

extern "C" void kernel_launch(void* const* d_in, const int* in_sizes, int n_in,
                              void* d_out, int out_size, void* d_ws, size_t ws_size,
                              hipStream_t stream) {
    const float* h   = (const float*)d_in[0];
    const int*   src = (const int*)d_in[1];
    const int*   dst = (const int*)d_in[2];
    const float* Wf  = (const float*)d_in[3];
    const float* Wa  = (const float*)d_in[4];
    const int N = in_sizes[0] / NODE_DIM;
    const int E = in_sizes[1];
    float* out = (float*)d_out;

    char* ws = (char*)d_ws;
    size_t off = 0;
    unsigned short* zbf = (unsigned short*)(ws + off); off += (size_t)N * OUT_DIM * sizeof(unsigned short);
    int*   spk    = (int*)(ws + off);   off += (size_t)E * sizeof(int);
    int*   rank   = (int*)(ws + off);   off += (size_t)E * sizeof(int);
    int*   deg    = (int*)(ws + off);   off += (size_t)N * sizeof(int);
    int*   rstart = (int*)(ws + off);   off += (size_t)N * sizeof(int);
    float* s_src  = (float*)(ws + off); off += (size_t)N * sizeof(float);
    float* s_dst  = (float*)(ws + off); off += (size_t)N * sizeof(float);
    int*   bsum   = (int*)(ws + off);   off += 256 * sizeof(int);

    const int PB = (N + 31) / 32;            // proj blocks (1563)
    const int CB = 1024;                     // count blocks
    const int nbN = (N + 255) / 256;         // 196
    const int nbE = (E + 255) / 256;

    hipMemsetAsync(deg, 0, (size_t)N * sizeof(int), stream);

    k_proj_count<<<PB + CB, 256, 0, stream>>>(h, Wf, Wa, zbf, s_src, s_dst,
                                              dst, deg, rank, N, E, PB, CB);
    k_scan_local<<<nbN, 256, 0, stream>>>(deg, rstart, bsum, N);
    k_scan_add<<<nbN, 256, 0, stream>>>(rstart, bsum, N, nbN);
    k_place<<<nbE, 256, 0, stream>>>(src, dst, rank, rstart, spk, E);
    k_agg<<<(N + 3) / 4, 256, 0, stream>>>(rstart, deg, spk, s_src, s_dst, zbf, out, N);
}